// Round 8
// baseline (287.519 us; speedup 1.0000x reference)
//
#include <hip/hip_runtime.h>

typedef __bf16 bf16;
typedef __bf16 bf16x4 __attribute__((ext_vector_type(4)));
typedef __bf16 bf16x8 __attribute__((ext_vector_type(8)));
typedef float f32x4 __attribute__((ext_vector_type(4)));

#define DIM 768
#define SEQ 2048
#define BATCH 2
#define NH 12
#define HD 64
#define M_TOT (BATCH*SEQ)   /* 4096 */
#define NQKV (3*DIM)        /* 2304 */
#define BK 32

__device__ __forceinline__ f32x4 mfma16(bf16x8 a, bf16x8 b, f32x4 c) {
    return __builtin_amdgcn_mfma_f32_16x16x32_bf16(a, b, c, 0, 0, 0);
}

// ---- async global->LDS staging of a 128x32 bf16 tile, XOR-swizzled (GEMMs) ----
// Single-buffer m97 structure. R7 showed dbuf regresses: compiler emits
// s_waitcnt vmcnt(0) before every s_barrier, so cross-buffer prefetch is
// drained at the next barrier anyway — dbuf only cost LDS/occupancy.
__device__ __forceinline__ void stage128x32(const bf16* g, int gstride, bf16* lds,
                                            int w, int lane) {
#pragma unroll
    for (int i = 0; i < 2; i++) {
        int p = (w*2 + i)*64 + lane;
        int r = p >> 2, c = p & 3;
        int s = c ^ ((r >> 1) & 3);
        __builtin_amdgcn_global_load_lds(
            (const __attribute__((address_space(1))) unsigned int*)(g + (size_t)r*gstride + s*8),
            (__attribute__((address_space(3))) unsigned int*)(lds + p*8),
            16, 0, 0);
    }
}
__device__ __forceinline__ bf16x8 frag128x32(const bf16* lds, int r, int quad) {
    int c = quad ^ ((r >> 1) & 3);
    return *(const bf16x8*)&lds[r*32 + c*8];
}

// ---------------- prep: x cast + tiled W transposes (fp32 -> bf16 [N][K]) ----------------
#define TQK_TILES ((DIM/32)*(NQKV/32))  /* 1728 */
#define TP_TILES  ((DIM/32)*(DIM/32))   /* 576  */
#define CAST_BLOCKS 768
__global__ __launch_bounds__(256) void prep_kernel(
    const float* __restrict__ x, const float* __restrict__ Wqkv,
    const float* __restrict__ Wproj,
    bf16* __restrict__ xb, bf16* __restrict__ Wqt, bf16* __restrict__ Wpt)
{
    const int bid = blockIdx.x;
    if (bid < TQK_TILES + TP_TILES) {
        const float* src; bf16* dst; int NN, KK, t;
        if (bid < TQK_TILES) { src = Wqkv; dst = Wqt; NN = NQKV; KK = DIM; t = bid; }
        else                 { src = Wproj; dst = Wpt; NN = DIM;  KK = DIM; t = bid - TQK_TILES; }
        const int ntn = NN / 32;
        const int tk = t / ntn, tn = t - tk * ntn;
        __shared__ float tile[32][33];
        const int tx = threadIdx.x & 31, ty = threadIdx.x >> 5;
#pragma unroll
        for (int i = 0; i < 4; i++)
            tile[ty + i*8][tx] = src[(size_t)(tk*32 + ty + i*8)*NN + tn*32 + tx];
        __syncthreads();
#pragma unroll
        for (int i = 0; i < 4; i++)
            dst[(size_t)(tn*32 + ty + i*8)*KK + tk*32 + tx] = (bf16)tile[tx][ty + i*8];
    } else {
        const int b2 = bid - (TQK_TILES + TP_TILES);
        const int N4 = M_TOT*DIM/4;
        for (int i = b2*256 + (int)threadIdx.x; i < N4; i += CAST_BLOCKS*256) {
            float4 v = ((const float4*)x)[i];
            bf16x4 o;
            o[0] = (bf16)v.x; o[1] = (bf16)v.y; o[2] = (bf16)v.z; o[3] = (bf16)v.w;
            *(bf16x4*)&xb[(size_t)i*4] = o;
        }
    }
}

// ---------------- QKV GEMM (single-buffer m97): Q,K -> [b][h][s][d]; V -> [b][h][d][s] ----------------
__global__ __launch_bounds__(256) void qkv_gemm(
    const bf16* __restrict__ A,
    const bf16* __restrict__ Bt,
    const float* __restrict__ bias,
    bf16* __restrict__ qkv)
{
    __shared__ bf16 As[128*32];
    __shared__ bf16 Bs[128*32];
    const int K = DIM;
    const int tid = threadIdx.x;
    const int row0 = blockIdx.y * 128, col0 = blockIdx.x * 128;
    const int w = tid >> 6, lane = tid & 63, quad = lane >> 4, l16 = lane & 15;
    const int wy = w >> 1, wx = w & 1;

    f32x4 acc[4][4];
#pragma unroll
    for (int mi = 0; mi < 4; mi++)
#pragma unroll
        for (int ni = 0; ni < 4; ni++)
            acc[mi][ni] = (f32x4){0.f,0.f,0.f,0.f};

    for (int k0 = 0; k0 < K; k0 += BK) {
        __syncthreads();
        stage128x32(A  + (size_t)row0*K + k0, K, As, w, lane);
        stage128x32(Bt + (size_t)col0*K + k0, K, Bs, w, lane);
        __syncthreads();
        bf16x8 af[4], bfv[4];
#pragma unroll
        for (int mi = 0; mi < 4; mi++)
            af[mi] = frag128x32(As, wy*64 + mi*16 + l16, quad);
#pragma unroll
        for (int ni = 0; ni < 4; ni++)
            bfv[ni] = frag128x32(Bs, wx*64 + ni*16 + l16, quad);
#pragma unroll
        for (int mi = 0; mi < 4; mi++)
#pragma unroll
            for (int ni = 0; ni < 4; ni++)
                acc[mi][ni] = mfma16(af[mi], bfv[ni], acc[mi][ni]);
    }

    const int which = col0 / DIM;
    if (which < 2) {
#pragma unroll
        for (int mi = 0; mi < 4; mi++)
#pragma unroll
            for (int ni = 0; ni < 4; ni++)
#pragma unroll
                for (int rr = 0; rr < 4; rr++) {
                    int r = row0 + wy*64 + mi*16 + quad*4 + rr;
                    int c = col0 + wx*64 + ni*16 + l16;
                    float v = acc[mi][ni][rr] + bias[c];
                    int cc = c - which*DIM;
                    int h = cc >> 6, d = cc & 63;
                    int bb = r >> 11, sq = r & (SEQ-1);
                    size_t idx = ((((size_t)which*BATCH + bb)*NH + h)*SEQ + sq)*HD + d;
                    qkv[idx] = (bf16)v;
                }
    } else {
        bf16* Vg = qkv + (size_t)2*BATCH*NH*SEQ*HD;  // V^T: [BATCH][NH][HD][SEQ]
#pragma unroll
        for (int mi = 0; mi < 4; mi++) {
            int r = row0 + wy*64 + mi*16 + quad*4;
            int bb = r >> 11, sq = r & (SEQ-1);
#pragma unroll
            for (int ni = 0; ni < 4; ni++) {
                int c = col0 + wx*64 + ni*16 + l16;
                int cc = c - 2*DIM;
                int h = cc >> 6, d = cc & 63;
                float bv = bias[c];
                bf16x4 tmp;
#pragma unroll
                for (int rr = 0; rr < 4; rr++)
                    tmp[rr] = (bf16)(acc[mi][ni][rr] + bv);
                size_t idx = (((size_t)bb*NH + h)*HD + d)*SEQ + sq;
                *(bf16x4*)&Vg[idx] = tmp;
            }
        }
    }
}

// ---------------- Flash attention v4: BARRIER-FREE — K/V fragments direct from global ----------------
// All 4 waves share the same 64-key tile; K [s][d] and V^T [d][s] layouts are
// MFMA-fragment-native, so LDS staging bought nothing but 2 barriers/tile.
// No __syncthreads anywhere -> compiler pipelines global loads with vmcnt(N).
// P round-trip stays in wave-private LDS (in-order within a wave, no barrier).
__global__ __launch_bounds__(256) void attn_kernel(
    const bf16* __restrict__ Q,   // [BATCH][NH][SEQ][HD]
    const bf16* __restrict__ Kb,  // [BATCH][NH][SEQ][HD]
    const bf16* __restrict__ Vb,  // [BATCH][NH][HD][SEQ]
    bf16* __restrict__ attnout,   // [4096][768]
    bf16* __restrict__ Opart,     // [24][24][2][64*64]
    float* __restrict__ lpart)    // [24][24][2][64]
{
    const int chunk = blockIdx.x;
    const int qt = 31 - (int)blockIdx.y;   // long blocks dispatch first
    const int bh = blockIdx.z;
    const int b = bh / NH, h = bh - b*NH;

    int kt0, kt1;
    if (qt < 8) { if (chunk) return; kt0 = 0; kt1 = qt; }
    else {
        int hh = (qt + 1) >> 1;
        if (chunk == 0) { kt0 = 0; kt1 = hh - 1; }
        else            { kt0 = hh; kt1 = qt; }
    }

    __shared__ bf16 Pl[4][16*72];     // per-wave P [qrow][key], stride 72

    const int tid = threadIdx.x, w = tid >> 6, lane = tid & 63;
    const int quad = lane >> 4, l16 = lane & 15;

    const size_t hoff = (size_t)bh*SEQ*HD;
    const bf16* Qh = Q + hoff;
    const bf16* Kh = Kb + hoff;
    const bf16* Vh = Vb + hoff;

    // persistent Q fragments (B-operand: lane l16 = qrow, k = ks*32 + quad*8 + j)
    const int qrow0 = qt*64 + w*16;
    bf16x8 qf0 = *(const bf16x8*)&Qh[(size_t)(qrow0 + l16)*HD + quad*8];
    bf16x8 qf1 = *(const bf16x8*)&Qh[(size_t)(qrow0 + l16)*HD + 32 + quad*8];

    f32x4 of[4];
#pragma unroll
    for (int i = 0; i < 4; i++) of[i] = (f32x4){0.f,0.f,0.f,0.f};
    float lsum = 0.f;

    const float SCL = 0.125f * 1.44269504088896f;  // 1/sqrt(64) * log2(e)
    bf16* pl = &Pl[w][0];

    for (int kt = kt0; kt <= kt1; kt++) {
        // S^T = K·Q^T — A-operand K fragments straight from global (L2-hot)
        f32x4 sf[4];
#pragma unroll
        for (int nt = 0; nt < 4; nt++) sf[nt] = (f32x4){0.f,0.f,0.f,0.f};
#pragma unroll
        for (int nt = 0; nt < 4; nt++) {
            const bf16* kr = &Kh[(size_t)(kt*64 + nt*16 + l16)*HD];
            bf16x8 kfa = *(const bf16x8*)&kr[quad*8];
            bf16x8 kfb = *(const bf16x8*)&kr[32 + quad*8];
            sf[nt] = mfma16(kfa, qf0, sf[nt]);
            sf[nt] = mfma16(kfb, qf1, sf[nt]);
        }

        // V^T B-operand fragments — issued before softmax so latency hides under it
        bf16x8 vva[4], vvb[4];
#pragma unroll
        for (int dm = 0; dm < 4; dm++) {
            const bf16* vr = &Vh[(size_t)(dm*16 + l16)*SEQ + kt*64];
            vva[dm] = *(const bf16x8*)&vr[quad*8];
            vvb[dm] = *(const bf16x8*)&vr[32 + quad*8];
        }

        // streaming softmax, fixed max=0; packed b64 P writes to [qrow][key]
        const bool diag = (kt == qt);
        const int qg = qt*64 + w*16 + l16;
#pragma unroll
        for (int nt = 0; nt < 4; nt++) {
            bf16x4 t4;
#pragma unroll
            for (int rr = 0; rr < 4; rr++) {
                float s = sf[nt][rr] * SCL;
                if (diag && (kt*64 + nt*16 + quad*4 + rr) > qg) s = -1e30f;
                float p = __builtin_amdgcn_exp2f(s);
                lsum += p;
                t4[rr] = (bf16)p;
            }
            *(bf16x4*)&pl[l16*72 + nt*16 + quad*4] = t4;
        }

        // O += P·V
        bf16x8 pa0 = *(const bf16x8*)&pl[l16*72 + quad*8];
        bf16x8 pa1 = *(const bf16x8*)&pl[l16*72 + 32 + quad*8];
#pragma unroll
        for (int dm = 0; dm < 4; dm++) {
            of[dm] = mfma16(pa0, vva[dm], of[dm]);
            of[dm] = mfma16(pa1, vvb[dm], of[dm]);
        }
    }

    lsum += __shfl_xor(lsum, 16);
    lsum += __shfl_xor(lsum, 32);

    if (qt < 8) {
        float linv[4];
#pragma unroll
        for (int rr = 0; rr < 4; rr++)
            linv[rr] = 1.0f / __shfl(lsum, quad*4 + rr);
#pragma unroll
        for (int rr = 0; rr < 4; rr++) {
            int g = b*SEQ + qt*64 + w*16 + quad*4 + rr;
#pragma unroll
            for (int dm = 0; dm < 4; dm++)
                attnout[(size_t)g*DIM + h*HD + dm*16 + l16] = (bf16)(of[dm][rr] * linv[rr]);
        }
    } else {
        size_t slot = ((size_t)bh*24 + (qt - 8))*2 + chunk;
        bf16* Os = Opart + slot*4096;
        float* ls = lpart + slot*64;
        if (quad == 0) ls[w*16 + l16] = lsum;
#pragma unroll
        for (int rr = 0; rr < 4; rr++) {
            int row = w*16 + quad*4 + rr;
#pragma unroll
            for (int dm = 0; dm < 4; dm++)
                Os[(size_t)row*64 + dm*16 + l16] = (bf16)of[dm][rr];
        }
    }
}

// ---------------- merge partials for qt>=8 ----------------
__global__ __launch_bounds__(256) void merge_kernel(
    const bf16* __restrict__ Opart, const float* __restrict__ lpart,
    bf16* __restrict__ attnout)
{
    const int qi = blockIdx.x;
    const int bh = blockIdx.y;
    const int b = bh / NH, h = bh - b*NH;
    const int t = threadIdx.x;
    const int row = t >> 2, cs = t & 3;

    size_t slot0 = ((size_t)bh*24 + qi)*2;
    const bf16* O0 = Opart + slot0*4096 + (size_t)row*64 + cs*16;
    const bf16* O1 = O0 + 4096;
    float inv = 1.0f / (lpart[slot0*64 + row] + lpart[(slot0+1)*64 + row]);

    bf16x8 a0 = *(const bf16x8*)O0;
    bf16x8 a1 = *(const bf16x8*)(O0 + 8);
    bf16x8 b0 = *(const bf16x8*)O1;
    bf16x8 b1 = *(const bf16x8*)(O1 + 8);
    bf16x8 o0, o1;
#pragma unroll
    for (int j = 0; j < 8; j++) {
        o0[j] = (bf16)(((float)a0[j] + (float)b0[j]) * inv);
        o1[j] = (bf16)(((float)a1[j] + (float)b1[j]) * inv);
    }
    size_t o = ((size_t)b*SEQ + (8 + qi)*64 + row)*DIM + h*HD + cs*16;
    *(bf16x8*)&attnout[o]     = o0;
    *(bf16x8*)&attnout[o + 8] = o1;
}

// ---------------- Proj GEMM (single-buffer m97): [4096,768]x[768,768]+bias -> fp32 ----------------
__global__ __launch_bounds__(256) void proj_gemm(
    const bf16* __restrict__ A,
    const bf16* __restrict__ Bt,
    const float* __restrict__ bias,
    float* __restrict__ out)
{
    __shared__ bf16 As[128*32];
    __shared__ bf16 Bs[128*32];
    const int K = DIM;
    const int tid = threadIdx.x;
    const int row0 = blockIdx.y * 128, col0 = blockIdx.x * 128;
    const int w = tid >> 6, lane = tid & 63, quad = lane >> 4, l16 = lane & 15;
    const int wy = w >> 1, wx = w & 1;

    f32x4 acc[4][4];
#pragma unroll
    for (int mi = 0; mi < 4; mi++)
#pragma unroll
        for (int ni = 0; ni < 4; ni++)
            acc[mi][ni] = (f32x4){0.f,0.f,0.f,0.f};

    for (int k0 = 0; k0 < K; k0 += BK) {
        __syncthreads();
        stage128x32(A  + (size_t)row0*K + k0, K, As, w, lane);
        stage128x32(Bt + (size_t)col0*K + k0, K, Bs, w, lane);
        __syncthreads();
        bf16x8 af[4], bfv[4];
#pragma unroll
        for (int mi = 0; mi < 4; mi++)
            af[mi] = frag128x32(As, wy*64 + mi*16 + l16, quad);
#pragma unroll
        for (int ni = 0; ni < 4; ni++)
            bfv[ni] = frag128x32(Bs, wx*64 + ni*16 + l16, quad);
#pragma unroll
        for (int mi = 0; mi < 4; mi++)
#pragma unroll
            for (int ni = 0; ni < 4; ni++)
                acc[mi][ni] = mfma16(af[mi], bfv[ni], acc[mi][ni]);
    }

#pragma unroll
    for (int mi = 0; mi < 4; mi++)
#pragma unroll
        for (int ni = 0; ni < 4; ni++)
#pragma unroll
            for (int rr = 0; rr < 4; rr++) {
                int r = row0 + wy*64 + mi*16 + quad*4 + rr;
                int c = col0 + wx*64 + ni*16 + l16;
                out[(size_t)r*DIM + c] = acc[mi][ni][rr] + bias[c];
            }
}

extern "C" void kernel_launch(void* const* d_in, const int* in_sizes, int n_in,
                              void* d_out, int out_size, void* d_ws, size_t ws_size,
                              hipStream_t stream) {
    const float* x     = (const float*)d_in[0];
    const float* Wqkv  = (const float*)d_in[1];
    const float* bqkv  = (const float*)d_in[2];
    const float* Wproj = (const float*)d_in[3];
    const float* bproj = (const float*)d_in[4];
    float* out = (float*)d_out;

    bf16* xb   = (bf16*)d_ws;                       // 4096*768     (dead after qkv_gemm)
    bf16* Wqt  = xb  + (size_t)M_TOT*DIM;           // 2304*768     (dead after qkv_gemm)
    bf16* Wpt  = Wqt + (size_t)NQKV*DIM;            // 768*768      (live until proj)
    bf16* qkvb = Wpt + (size_t)DIM*DIM;             // 3*4096*768
    bf16* attn = qkvb + (size_t)3*M_TOT*DIM;        // 4096*768

    bf16*  Opart = xb;
    float* lpart = (float*)(xb + (size_t)24*24*2*4096);

    const size_t headsz = (size_t)BATCH*NH*SEQ*HD;

    prep_kernel<<<TQK_TILES + TP_TILES + CAST_BLOCKS, 256, 0, stream>>>(
        x, Wqkv, Wproj, xb, Wqt, Wpt);
    qkv_gemm<<<dim3(NQKV/128, M_TOT/128), 256, 0, stream>>>(xb, Wqt, bqkv, qkvb);
    attn_kernel<<<dim3(2, SEQ/64, BATCH*NH), 256, 0, stream>>>(
        qkvb, qkvb + headsz, qkvb + 2*headsz, attn, Opart, lpart);
    merge_kernel<<<dim3(24, BATCH*NH), 256, 0, stream>>>(Opart, lpart, attn);
    proj_gemm<<<dim3(DIM/128, M_TOT/128), 256, 0, stream>>>(attn, Wpt, bproj, out);
}

// Round 9
// 233.159 us; speedup vs baseline: 1.2331x; 1.2331x over previous
//
#include <hip/hip_runtime.h>

typedef __bf16 bf16;
typedef __bf16 bf16x4 __attribute__((ext_vector_type(4)));
typedef __bf16 bf16x8 __attribute__((ext_vector_type(8)));
typedef float f32x4 __attribute__((ext_vector_type(4)));

#define DIM 768
#define SEQ 2048
#define BATCH 2
#define NH 12
#define HD 64
#define M_TOT (BATCH*SEQ)   /* 4096 */
#define NQKV (3*DIM)        /* 2304 */
#define BK 32

__device__ __forceinline__ f32x4 mfma16(bf16x8 a, bf16x8 b, f32x4 c) {
    return __builtin_amdgcn_mfma_f32_16x16x32_bf16(a, b, c, 0, 0, 0);
}

// ---- async global->LDS staging of a 128x32 bf16 tile, XOR-swizzled (GEMMs) ----
// Single-buffer m97 structure (R7 dbuf regressed: vmcnt(0) drain before every
// s_barrier defeats cross-buffer prefetch; dbuf only cost LDS/occupancy).
__device__ __forceinline__ void stage128x32(const bf16* g, int gstride, bf16* lds,
                                            int w, int lane) {
#pragma unroll
    for (int i = 0; i < 2; i++) {
        int p = (w*2 + i)*64 + lane;
        int r = p >> 2, c = p & 3;
        int s = c ^ ((r >> 1) & 3);
        __builtin_amdgcn_global_load_lds(
            (const __attribute__((address_space(1))) unsigned int*)(g + (size_t)r*gstride + s*8),
            (__attribute__((address_space(3))) unsigned int*)(lds + p*8),
            16, 0, 0);
    }
}
__device__ __forceinline__ bf16x8 frag128x32(const bf16* lds, int r, int quad) {
    int c = quad ^ ((r >> 1) & 3);
    return *(const bf16x8*)&lds[r*32 + c*8];
}

// ---------------- prep: x cast + tiled W transposes (fp32 -> bf16 [N][K]) ----------------
#define TQK_TILES ((DIM/32)*(NQKV/32))  /* 1728 */
#define TP_TILES  ((DIM/32)*(DIM/32))   /* 576  */
#define CAST_BLOCKS 768
__global__ __launch_bounds__(256) void prep_kernel(
    const float* __restrict__ x, const float* __restrict__ Wqkv,
    const float* __restrict__ Wproj,
    bf16* __restrict__ xb, bf16* __restrict__ Wqt, bf16* __restrict__ Wpt)
{
    const int bid = blockIdx.x;
    if (bid < TQK_TILES + TP_TILES) {
        const float* src; bf16* dst; int NN, KK, t;
        if (bid < TQK_TILES) { src = Wqkv; dst = Wqt; NN = NQKV; KK = DIM; t = bid; }
        else                 { src = Wproj; dst = Wpt; NN = DIM;  KK = DIM; t = bid - TQK_TILES; }
        const int ntn = NN / 32;
        const int tk = t / ntn, tn = t - tk * ntn;
        __shared__ float tile[32][33];
        const int tx = threadIdx.x & 31, ty = threadIdx.x >> 5;
#pragma unroll
        for (int i = 0; i < 4; i++)
            tile[ty + i*8][tx] = src[(size_t)(tk*32 + ty + i*8)*NN + tn*32 + tx];
        __syncthreads();
#pragma unroll
        for (int i = 0; i < 4; i++)
            dst[(size_t)(tn*32 + ty + i*8)*KK + tk*32 + tx] = (bf16)tile[tx][ty + i*8];
    } else {
        const int b2 = bid - (TQK_TILES + TP_TILES);
        const int N4 = M_TOT*DIM/4;
        for (int i = b2*256 + (int)threadIdx.x; i < N4; i += CAST_BLOCKS*256) {
            float4 v = ((const float4*)x)[i];
            bf16x4 o;
            o[0] = (bf16)v.x; o[1] = (bf16)v.y; o[2] = (bf16)v.z; o[3] = (bf16)v.w;
            *(bf16x4*)&xb[(size_t)i*4] = o;
        }
    }
}

// ---------------- QKV GEMM (single-buffer m97): Q,K -> [b][h][s][d]; V -> [b][h][d][s] ----------------
__global__ __launch_bounds__(256) void qkv_gemm(
    const bf16* __restrict__ A,
    const bf16* __restrict__ Bt,
    const float* __restrict__ bias,
    bf16* __restrict__ qkv)
{
    __shared__ bf16 As[128*32];
    __shared__ bf16 Bs[128*32];
    const int K = DIM;
    const int tid = threadIdx.x;
    const int row0 = blockIdx.y * 128, col0 = blockIdx.x * 128;
    const int w = tid >> 6, lane = tid & 63, quad = lane >> 4, l16 = lane & 15;
    const int wy = w >> 1, wx = w & 1;

    f32x4 acc[4][4];
#pragma unroll
    for (int mi = 0; mi < 4; mi++)
#pragma unroll
        for (int ni = 0; ni < 4; ni++)
            acc[mi][ni] = (f32x4){0.f,0.f,0.f,0.f};

    for (int k0 = 0; k0 < K; k0 += BK) {
        __syncthreads();
        stage128x32(A  + (size_t)row0*K + k0, K, As, w, lane);
        stage128x32(Bt + (size_t)col0*K + k0, K, Bs, w, lane);
        __syncthreads();
        bf16x8 af[4], bfv[4];
#pragma unroll
        for (int mi = 0; mi < 4; mi++)
            af[mi] = frag128x32(As, wy*64 + mi*16 + l16, quad);
#pragma unroll
        for (int ni = 0; ni < 4; ni++)
            bfv[ni] = frag128x32(Bs, wx*64 + ni*16 + l16, quad);
#pragma unroll
        for (int mi = 0; mi < 4; mi++)
#pragma unroll
            for (int ni = 0; ni < 4; ni++)
                acc[mi][ni] = mfma16(af[mi], bfv[ni], acc[mi][ni]);
    }

    const int which = col0 / DIM;
    if (which < 2) {
#pragma unroll
        for (int mi = 0; mi < 4; mi++)
#pragma unroll
            for (int ni = 0; ni < 4; ni++)
#pragma unroll
                for (int rr = 0; rr < 4; rr++) {
                    int r = row0 + wy*64 + mi*16 + quad*4 + rr;
                    int c = col0 + wx*64 + ni*16 + l16;
                    float v = acc[mi][ni][rr] + bias[c];
                    int cc = c - which*DIM;
                    int h = cc >> 6, d = cc & 63;
                    int bb = r >> 11, sq = r & (SEQ-1);
                    size_t idx = ((((size_t)which*BATCH + bb)*NH + h)*SEQ + sq)*HD + d;
                    qkv[idx] = (bf16)v;
                }
    } else {
        bf16* Vg = qkv + (size_t)2*BATCH*NH*SEQ*HD;  // V^T: [BATCH][NH][HD][SEQ]
#pragma unroll
        for (int mi = 0; mi < 4; mi++) {
            int r = row0 + wy*64 + mi*16 + quad*4;
            int bb = r >> 11, sq = r & (SEQ-1);
#pragma unroll
            for (int ni = 0; ni < 4; ni++) {
                int c = col0 + wx*64 + ni*16 + l16;
                int cc = c - 2*DIM;
                int h = cc >> 6, d = cc & 63;
                float bv = bias[c];
                bf16x4 tmp;
#pragma unroll
                for (int rr = 0; rr < 4; rr++)
                    tmp[rr] = (bf16)(acc[mi][ni][rr] + bv);
                size_t idx = (((size_t)bb*NH + h)*HD + d)*SEQ + sq;
                *(bf16x4*)&Vg[idx] = tmp;
            }
        }
    }
}

// ---------------- Flash attention v5: 2 waves x 32 q-rows — K/V LDS reads halved ----------------
// Same grid/chunking/partials as R6. 128-thread blocks; each wave owns 32 q-rows
// (2 q-groups of 16). K/V fragments loaded once per nt/dm, reused for both
// q-groups -> block-tile LDS read traffic ~halved vs 4-wave version. Barriers
// sync only 2 waves. Diag masking VALU runs only on the diagonal tile.
__global__ __launch_bounds__(128) void attn_kernel(
    const bf16* __restrict__ Q,   // [BATCH][NH][SEQ][HD]
    const bf16* __restrict__ Kb,  // [BATCH][NH][SEQ][HD]
    const bf16* __restrict__ Vb,  // [BATCH][NH][HD][SEQ]
    bf16* __restrict__ attnout,   // [4096][768]
    bf16* __restrict__ Opart,     // [24][24][2][64*64]
    float* __restrict__ lpart)    // [24][24][2][64]
{
    const int chunk = blockIdx.x;
    const int qt = 31 - (int)blockIdx.y;   // long blocks dispatch first
    const int bh = blockIdx.z;
    const int b = bh / NH, h = bh - b*NH;

    int kt0, kt1;
    if (qt < 8) { if (chunk) return; kt0 = 0; kt1 = qt; }
    else {
        int hh = (qt + 1) >> 1;
        if (chunk == 0) { kt0 = 0; kt1 = hh - 1; }
        else            { kt0 = hh; kt1 = qt; }
    }

    __shared__ bf16 Kt[64*64];        // [key][d], 16B granules XOR-swizzled by (row&7)
    __shared__ bf16 Vt[64*64];        // [d][key], same swizzle
    __shared__ bf16 Pl[2][2*16*72];   // [wave][qg][qrow 16][key, stride 72]

    const int tid = threadIdx.x, w = tid >> 6, lane = tid & 63;
    const int quad = lane >> 4, l16 = lane & 15;

    const size_t hoff = (size_t)bh*SEQ*HD;
    const bf16* Qh = Q + hoff;
    const bf16* Kh = Kb + hoff;
    const bf16* Vh = Vb + hoff;

    // persistent Q fragments: 2 q-groups x 2 k-halves (B-operand: l16 = qrow)
    bf16x8 qf[2][2];
#pragma unroll
    for (int qg = 0; qg < 2; qg++) {
        const bf16* qr = &Qh[(size_t)(qt*64 + w*32 + qg*16 + l16)*HD];
        qf[qg][0] = *(const bf16x8*)&qr[quad*8];
        qf[qg][1] = *(const bf16x8*)&qr[32 + quad*8];
    }

    f32x4 of[2][4];
#pragma unroll
    for (int qg = 0; qg < 2; qg++)
#pragma unroll
        for (int i = 0; i < 4; i++) of[qg][i] = (f32x4){0.f,0.f,0.f,0.f};
    float lsum[2] = {0.f, 0.f};

    // staging geometry: 128 threads, 4 K granules + 4 V granules each
    uint4 kpre[4], vpre[4];
#pragma unroll
    for (int i = 0; i < 4; i++) {
        int p = tid + i*128;
        int r = p >> 3, s = (p & 7) ^ (r & 7);
        kpre[i] = *(const uint4*)&Kh[(size_t)(kt0*64 + r)*HD + s*8];
        vpre[i] = *(const uint4*)&Vh[(size_t)r*SEQ + kt0*64 + s*8];
    }

    const float SCL = 0.125f * 1.44269504088896f;  // 1/sqrt(64) * log2(e)
    bf16* pl = &Pl[w][0];

    for (int kt = kt0; kt <= kt1; kt++) {
        __syncthreads();                       // prev readers done
#pragma unroll
        for (int i = 0; i < 4; i++) {
            int p = tid + i*128;
            *(uint4*)&Kt[p*8] = kpre[i];
            *(uint4*)&Vt[p*8] = vpre[i];
        }
        __syncthreads();                       // tiles visible

        if (kt < kt1) {                        // prefetch next tile under compute
#pragma unroll
            for (int i = 0; i < 4; i++) {
                int p = tid + i*128;
                int r = p >> 3, s = (p & 7) ^ (r & 7);
                kpre[i] = *(const uint4*)&Kh[(size_t)((kt+1)*64 + r)*HD + s*8];
                vpre[i] = *(const uint4*)&Vh[(size_t)r*SEQ + (kt+1)*64 + s*8];
            }
        }

        // S^T = K·Q^T : K frags loaded once, reused for both q-groups
        f32x4 sf[2][4];
#pragma unroll
        for (int qg = 0; qg < 2; qg++)
#pragma unroll
            for (int nt = 0; nt < 4; nt++) sf[qg][nt] = (f32x4){0.f,0.f,0.f,0.f};
#pragma unroll
        for (int nt = 0; nt < 4; nt++) {
            int r = nt*16 + l16;
            bf16x8 kfa = *(const bf16x8*)&Kt[r*64 + ((quad ^ (r&7))*8)];
            bf16x8 kfb = *(const bf16x8*)&Kt[r*64 + (((4+quad) ^ (r&7))*8)];
#pragma unroll
            for (int qg = 0; qg < 2; qg++) {
                sf[qg][nt] = mfma16(kfa, qf[qg][0], sf[qg][nt]);
                sf[qg][nt] = mfma16(kfb, qf[qg][1], sf[qg][nt]);
            }
        }

        // streaming softmax, fixed max=0; diag masking only on the diagonal tile
        if (kt == qt) {
#pragma unroll
            for (int qg = 0; qg < 2; qg++) {
                bf16* pq = pl + qg*1152;
                const int qrow = qt*64 + w*32 + qg*16 + l16;
#pragma unroll
                for (int nt = 0; nt < 4; nt++) {
                    bf16x4 t4;
#pragma unroll
                    for (int rr = 0; rr < 4; rr++) {
                        float s = sf[qg][nt][rr] * SCL;
                        if ((kt*64 + nt*16 + quad*4 + rr) > qrow) s = -1e30f;
                        float p = __builtin_amdgcn_exp2f(s);
                        lsum[qg] += p;
                        t4[rr] = (bf16)p;
                    }
                    *(bf16x4*)&pq[l16*72 + nt*16 + quad*4] = t4;
                }
            }
        } else {
#pragma unroll
            for (int qg = 0; qg < 2; qg++) {
                bf16* pq = pl + qg*1152;
#pragma unroll
                for (int nt = 0; nt < 4; nt++) {
                    bf16x4 t4;
#pragma unroll
                    for (int rr = 0; rr < 4; rr++) {
                        float p = __builtin_amdgcn_exp2f(sf[qg][nt][rr] * SCL);
                        lsum[qg] += p;
                        t4[rr] = (bf16)p;
                    }
                    *(bf16x4*)&pq[l16*72 + nt*16 + quad*4] = t4;
                }
            }
        }

        // O += P·V : V frags loaded once, reused for both q-groups
        bf16x8 pa[2][2];
#pragma unroll
        for (int qg = 0; qg < 2; qg++) {
            pa[qg][0] = *(const bf16x8*)&pl[qg*1152 + l16*72 + quad*8];
            pa[qg][1] = *(const bf16x8*)&pl[qg*1152 + l16*72 + 32 + quad*8];
        }
#pragma unroll
        for (int dm = 0; dm < 4; dm++) {
            int r = dm*16 + l16;
            bf16x8 vva = *(const bf16x8*)&Vt[r*64 + ((quad ^ (r&7))*8)];
            bf16x8 vvb = *(const bf16x8*)&Vt[r*64 + (((4+quad) ^ (r&7))*8)];
#pragma unroll
            for (int qg = 0; qg < 2; qg++) {
                of[qg][dm] = mfma16(pa[qg][0], vva, of[qg][dm]);
                of[qg][dm] = mfma16(pa[qg][1], vvb, of[qg][dm]);
            }
        }
    }

    // epilogue per q-group
#pragma unroll
    for (int qg = 0; qg < 2; qg++) {
        float ls = lsum[qg];
        ls += __shfl_xor(ls, 16);
        ls += __shfl_xor(ls, 32);
        if (qt < 8) {
            float linv[4];
#pragma unroll
            for (int rr = 0; rr < 4; rr++)
                linv[rr] = 1.0f / __shfl(ls, quad*4 + rr);
#pragma unroll
            for (int rr = 0; rr < 4; rr++) {
                int g = b*SEQ + qt*64 + w*32 + qg*16 + quad*4 + rr;
#pragma unroll
                for (int dm = 0; dm < 4; dm++)
                    attnout[(size_t)g*DIM + h*HD + dm*16 + l16] = (bf16)(of[qg][dm][rr] * linv[rr]);
            }
        } else {
            size_t slot = ((size_t)bh*24 + (qt - 8))*2 + chunk;
            bf16* Os = Opart + slot*4096;
            float* lsp = lpart + slot*64;
            if (quad == 0) lsp[w*32 + qg*16 + l16] = ls;
#pragma unroll
            for (int rr = 0; rr < 4; rr++) {
                int row = w*32 + qg*16 + quad*4 + rr;
#pragma unroll
                for (int dm = 0; dm < 4; dm++)
                    Os[(size_t)row*64 + dm*16 + l16] = (bf16)of[qg][dm][rr];
            }
        }
    }
}

// ---------------- merge partials for qt>=8 ----------------
__global__ __launch_bounds__(256) void merge_kernel(
    const bf16* __restrict__ Opart, const float* __restrict__ lpart,
    bf16* __restrict__ attnout)
{
    const int qi = blockIdx.x;
    const int bh = blockIdx.y;
    const int b = bh / NH, h = bh - b*NH;
    const int t = threadIdx.x;
    const int row = t >> 2, cs = t & 3;

    size_t slot0 = ((size_t)bh*24 + qi)*2;
    const bf16* O0 = Opart + slot0*4096 + (size_t)row*64 + cs*16;
    const bf16* O1 = O0 + 4096;
    float inv = 1.0f / (lpart[slot0*64 + row] + lpart[(slot0+1)*64 + row]);

    bf16x8 a0 = *(const bf16x8*)O0;
    bf16x8 a1 = *(const bf16x8*)(O0 + 8);
    bf16x8 b0 = *(const bf16x8*)O1;
    bf16x8 b1 = *(const bf16x8*)(O1 + 8);
    bf16x8 o0, o1;
#pragma unroll
    for (int j = 0; j < 8; j++) {
        o0[j] = (bf16)(((float)a0[j] + (float)b0[j]) * inv);
        o1[j] = (bf16)(((float)a1[j] + (float)b1[j]) * inv);
    }
    size_t o = ((size_t)b*SEQ + (8 + qi)*64 + row)*DIM + h*HD + cs*16;
    *(bf16x8*)&attnout[o]     = o0;
    *(bf16x8*)&attnout[o + 8] = o1;
}

// ---------------- Proj GEMM (single-buffer m97): [4096,768]x[768,768]+bias -> fp32 ----------------
__global__ __launch_bounds__(256) void proj_gemm(
    const bf16* __restrict__ A,
    const bf16* __restrict__ Bt,
    const float* __restrict__ bias,
    float* __restrict__ out)
{
    __shared__ bf16 As[128*32];
    __shared__ bf16 Bs[128*32];
    const int K = DIM;
    const int tid = threadIdx.x;
    const int row0 = blockIdx.y * 128, col0 = blockIdx.x * 128;
    const int w = tid >> 6, lane = tid & 63, quad = lane >> 4, l16 = lane & 15;
    const int wy = w >> 1, wx = w & 1;

    f32x4 acc[4][4];
#pragma unroll
    for (int mi = 0; mi < 4; mi++)
#pragma unroll
        for (int ni = 0; ni < 4; ni++)
            acc[mi][ni] = (f32x4){0.f,0.f,0.f,0.f};

    for (int k0 = 0; k0 < K; k0 += BK) {
        __syncthreads();
        stage128x32(A  + (size_t)row0*K + k0, K, As, w, lane);
        stage128x32(Bt + (size_t)col0*K + k0, K, Bs, w, lane);
        __syncthreads();
        bf16x8 af[4], bfv[4];
#pragma unroll
        for (int mi = 0; mi < 4; mi++)
            af[mi] = frag128x32(As, wy*64 + mi*16 + l16, quad);
#pragma unroll
        for (int ni = 0; ni < 4; ni++)
            bfv[ni] = frag128x32(Bs, wx*64 + ni*16 + l16, quad);
#pragma unroll
        for (int mi = 0; mi < 4; mi++)
#pragma unroll
            for (int ni = 0; ni < 4; ni++)
                acc[mi][ni] = mfma16(af[mi], bfv[ni], acc[mi][ni]);
    }

#pragma unroll
    for (int mi = 0; mi < 4; mi++)
#pragma unroll
        for (int ni = 0; ni < 4; ni++)
#pragma unroll
            for (int rr = 0; rr < 4; rr++) {
                int r = row0 + wy*64 + mi*16 + quad*4 + rr;
                int c = col0 + wx*64 + ni*16 + l16;
                out[(size_t)r*DIM + c] = acc[mi][ni][rr] + bias[c];
            }
}

extern "C" void kernel_launch(void* const* d_in, const int* in_sizes, int n_in,
                              void* d_out, int out_size, void* d_ws, size_t ws_size,
                              hipStream_t stream) {
    const float* x     = (const float*)d_in[0];
    const float* Wqkv  = (const float*)d_in[1];
    const float* bqkv  = (const float*)d_in[2];
    const float* Wproj = (const float*)d_in[3];
    const float* bproj = (const float*)d_in[4];
    float* out = (float*)d_out;

    bf16* xb   = (bf16*)d_ws;                       // 4096*768     (dead after qkv_gemm)
    bf16* Wqt  = xb  + (size_t)M_TOT*DIM;           // 2304*768     (dead after qkv_gemm)
    bf16* Wpt  = Wqt + (size_t)NQKV*DIM;            // 768*768      (live until proj)
    bf16* qkvb = Wpt + (size_t)DIM*DIM;             // 3*4096*768
    bf16* attn = qkvb + (size_t)3*M_TOT*DIM;        // 4096*768

    bf16*  Opart = xb;
    float* lpart = (float*)(xb + (size_t)24*24*2*4096);

    const size_t headsz = (size_t)BATCH*NH*SEQ*HD;

    prep_kernel<<<TQK_TILES + TP_TILES + CAST_BLOCKS, 256, 0, stream>>>(
        x, Wqkv, Wproj, xb, Wqt, Wpt);
    qkv_gemm<<<dim3(NQKV/128, M_TOT/128), 256, 0, stream>>>(xb, Wqt, bqkv, qkvb);
    attn_kernel<<<dim3(2, SEQ/64, BATCH*NH), 128, 0, stream>>>(
        qkvb, qkvb + headsz, qkvb + 2*headsz, attn, Opart, lpart);
    merge_kernel<<<dim3(24, BATCH*NH), 256, 0, stream>>>(Opart, lpart, attn);
    proj_gemm<<<dim3(DIM/128, M_TOT/128), 256, 0, stream>>>(attn, Wpt, bproj, out);
}

// Round 10
// 161.553 us; speedup vs baseline: 1.7797x; 1.4432x over previous
//
#include <hip/hip_runtime.h>

typedef __bf16 bf16;
typedef __bf16 bf16x4 __attribute__((ext_vector_type(4)));
typedef __bf16 bf16x8 __attribute__((ext_vector_type(8)));
typedef float f32x4 __attribute__((ext_vector_type(4)));

#define DIM 768
#define SEQ 2048
#define BATCH 2
#define NH 12
#define HD 64
#define M_TOT (BATCH*SEQ)   /* 4096 */
#define NQKV (3*DIM)        /* 2304 */
#define BK 32

__device__ __forceinline__ f32x4 mfma16(bf16x8 a, bf16x8 b, f32x4 c) {
    return __builtin_amdgcn_mfma_f32_16x16x32_bf16(a, b, c, 0, 0, 0);
}

// ---- async global->LDS staging of a 128x32 bf16 tile, XOR-swizzled (GEMMs) ----
// Single-buffer m97 structure. R7: dbuf regresses (vmcnt(0) drain before every
// s_barrier defeats cross-buffer prefetch). R8: direct-global frags regress
// (strided 64B segments, un-prefetched latency). R9: 2-wave attn regresses
// (VGPR spill -> 112MB scratch). R6 config is the measured optimum: 162 us.
__device__ __forceinline__ void stage128x32(const bf16* g, int gstride, bf16* lds,
                                            int w, int lane) {
#pragma unroll
    for (int i = 0; i < 2; i++) {
        int p = (w*2 + i)*64 + lane;
        int r = p >> 2, c = p & 3;
        int s = c ^ ((r >> 1) & 3);
        __builtin_amdgcn_global_load_lds(
            (const __attribute__((address_space(1))) unsigned int*)(g + (size_t)r*gstride + s*8),
            (__attribute__((address_space(3))) unsigned int*)(lds + p*8),
            16, 0, 0);
    }
}
__device__ __forceinline__ bf16x8 frag128x32(const bf16* lds, int r, int quad) {
    int c = quad ^ ((r >> 1) & 3);
    return *(const bf16x8*)&lds[r*32 + c*8];
}

// ---------------- prep: x cast + tiled W transposes (fp32 -> bf16 [N][K]) ----------------
#define TQK_TILES ((DIM/32)*(NQKV/32))  /* 1728 */
#define TP_TILES  ((DIM/32)*(DIM/32))   /* 576  */
#define CAST_BLOCKS 768
__global__ __launch_bounds__(256) void prep_kernel(
    const float* __restrict__ x, const float* __restrict__ Wqkv,
    const float* __restrict__ Wproj,
    bf16* __restrict__ xb, bf16* __restrict__ Wqt, bf16* __restrict__ Wpt)
{
    const int bid = blockIdx.x;
    if (bid < TQK_TILES + TP_TILES) {
        const float* src; bf16* dst; int NN, KK, t;
        if (bid < TQK_TILES) { src = Wqkv; dst = Wqt; NN = NQKV; KK = DIM; t = bid; }
        else                 { src = Wproj; dst = Wpt; NN = DIM;  KK = DIM; t = bid - TQK_TILES; }
        const int ntn = NN / 32;
        const int tk = t / ntn, tn = t - tk * ntn;
        __shared__ float tile[32][33];
        const int tx = threadIdx.x & 31, ty = threadIdx.x >> 5;
#pragma unroll
        for (int i = 0; i < 4; i++)
            tile[ty + i*8][tx] = src[(size_t)(tk*32 + ty + i*8)*NN + tn*32 + tx];
        __syncthreads();
#pragma unroll
        for (int i = 0; i < 4; i++)
            dst[(size_t)(tn*32 + ty + i*8)*KK + tk*32 + tx] = (bf16)tile[tx][ty + i*8];
    } else {
        const int b2 = bid - (TQK_TILES + TP_TILES);
        const int N4 = M_TOT*DIM/4;
        for (int i = b2*256 + (int)threadIdx.x; i < N4; i += CAST_BLOCKS*256) {
            float4 v = ((const float4*)x)[i];
            bf16x4 o;
            o[0] = (bf16)v.x; o[1] = (bf16)v.y; o[2] = (bf16)v.z; o[3] = (bf16)v.w;
            *(bf16x4*)&xb[(size_t)i*4] = o;
        }
    }
}

// ---------------- QKV GEMM (single-buffer m97): Q,K -> [b][h][s][d]; V -> [b][h][d][s] ----------------
__global__ __launch_bounds__(256) void qkv_gemm(
    const bf16* __restrict__ A,
    const bf16* __restrict__ Bt,
    const float* __restrict__ bias,
    bf16* __restrict__ qkv)
{
    __shared__ bf16 As[128*32];
    __shared__ bf16 Bs[128*32];
    const int K = DIM;
    const int tid = threadIdx.x;
    const int row0 = blockIdx.y * 128, col0 = blockIdx.x * 128;
    const int w = tid >> 6, lane = tid & 63, quad = lane >> 4, l16 = lane & 15;
    const int wy = w >> 1, wx = w & 1;

    f32x4 acc[4][4];
#pragma unroll
    for (int mi = 0; mi < 4; mi++)
#pragma unroll
        for (int ni = 0; ni < 4; ni++)
            acc[mi][ni] = (f32x4){0.f,0.f,0.f,0.f};

    for (int k0 = 0; k0 < K; k0 += BK) {
        __syncthreads();
        stage128x32(A  + (size_t)row0*K + k0, K, As, w, lane);
        stage128x32(Bt + (size_t)col0*K + k0, K, Bs, w, lane);
        __syncthreads();
        bf16x8 af[4], bfv[4];
#pragma unroll
        for (int mi = 0; mi < 4; mi++)
            af[mi] = frag128x32(As, wy*64 + mi*16 + l16, quad);
#pragma unroll
        for (int ni = 0; ni < 4; ni++)
            bfv[ni] = frag128x32(Bs, wx*64 + ni*16 + l16, quad);
#pragma unroll
        for (int mi = 0; mi < 4; mi++)
#pragma unroll
            for (int ni = 0; ni < 4; ni++)
                acc[mi][ni] = mfma16(af[mi], bfv[ni], acc[mi][ni]);
    }

    const int which = col0 / DIM;
    if (which < 2) {
#pragma unroll
        for (int mi = 0; mi < 4; mi++)
#pragma unroll
            for (int ni = 0; ni < 4; ni++)
#pragma unroll
                for (int rr = 0; rr < 4; rr++) {
                    int r = row0 + wy*64 + mi*16 + quad*4 + rr;
                    int c = col0 + wx*64 + ni*16 + l16;
                    float v = acc[mi][ni][rr] + bias[c];
                    int cc = c - which*DIM;
                    int h = cc >> 6, d = cc & 63;
                    int bb = r >> 11, sq = r & (SEQ-1);
                    size_t idx = ((((size_t)which*BATCH + bb)*NH + h)*SEQ + sq)*HD + d;
                    qkv[idx] = (bf16)v;
                }
    } else {
        bf16* Vg = qkv + (size_t)2*BATCH*NH*SEQ*HD;  // V^T: [BATCH][NH][HD][SEQ]
#pragma unroll
        for (int mi = 0; mi < 4; mi++) {
            int r = row0 + wy*64 + mi*16 + quad*4;
            int bb = r >> 11, sq = r & (SEQ-1);
#pragma unroll
            for (int ni = 0; ni < 4; ni++) {
                int c = col0 + wx*64 + ni*16 + l16;
                int cc = c - 2*DIM;
                int h = cc >> 6, d = cc & 63;
                float bv = bias[c];
                bf16x4 tmp;
#pragma unroll
                for (int rr = 0; rr < 4; rr++)
                    tmp[rr] = (bf16)(acc[mi][ni][rr] + bv);
                size_t idx = (((size_t)bb*NH + h)*HD + d)*SEQ + sq;
                *(bf16x4*)&Vg[idx] = tmp;
            }
        }
    }
}

// ---------------- Flash attention v3b (R6-proven): S^T form, reg-prefetch, swizzled LDS ----------------
// grid (chunk=2, qt=32, bh=24). qt<8: single chunk direct-write.
// qt>=8: 2 balanced chunks -> partials merged by merge_kernel.
// 4 waves x 16 q-rows, 256 threads. No launch-bounds cap (R4/R5 spill lesson);
// all packed stores via ext_vector types (SROA-safe, R6 lesson).
__global__ __launch_bounds__(256) void attn_kernel(
    const bf16* __restrict__ Q,   // [BATCH][NH][SEQ][HD]
    const bf16* __restrict__ Kb,  // [BATCH][NH][SEQ][HD]
    const bf16* __restrict__ Vb,  // [BATCH][NH][HD][SEQ]
    bf16* __restrict__ attnout,   // [4096][768]
    bf16* __restrict__ Opart,     // [24][24][2][64*64]
    float* __restrict__ lpart)    // [24][24][2][64]
{
    const int chunk = blockIdx.x;
    const int qt = 31 - (int)blockIdx.y;   // long blocks dispatch first
    const int bh = blockIdx.z;
    const int b = bh / NH, h = bh - b*NH;

    int kt0, kt1;
    if (qt < 8) { if (chunk) return; kt0 = 0; kt1 = qt; }
    else {
        int hh = (qt + 1) >> 1;
        if (chunk == 0) { kt0 = 0; kt1 = hh - 1; }
        else            { kt0 = hh; kt1 = qt; }
    }

    __shared__ bf16 Kt[64*64];        // [key][d], 16B granules XOR-swizzled by (row&7)
    __shared__ bf16 Vt[64*64];        // [d][key], same swizzle
    __shared__ bf16 Pl[4][16*72];     // per-wave P [qrow][key], stride 72

    const int tid = threadIdx.x, w = tid >> 6, lane = tid & 63;
    const int quad = lane >> 4, l16 = lane & 15;

    const size_t hoff = (size_t)bh*SEQ*HD;
    const bf16* Qh = Q + hoff;
    const bf16* Kh = Kb + hoff;
    const bf16* Vh = Vb + hoff;

    const int qrow0 = qt*64 + w*16;
    bf16x8 qf0 = *(const bf16x8*)&Qh[(size_t)(qrow0 + l16)*HD + quad*8];
    bf16x8 qf1 = *(const bf16x8*)&Qh[(size_t)(qrow0 + l16)*HD + 32 + quad*8];

    f32x4 of[4];
#pragma unroll
    for (int i = 0; i < 4; i++) of[i] = (f32x4){0.f,0.f,0.f,0.f};
    float lsum = 0.f;

    const int p0 = w*128 + lane;
    const int r0 = p0 >> 3, s0 = (p0 & 7) ^ (r0 & 7);
    const int p1 = p0 + 64;
    const int r1 = p1 >> 3, s1 = (p1 & 7) ^ (r1 & 7);

    uint4 kpre0 = *(const uint4*)&Kh[(size_t)(kt0*64 + r0)*HD + s0*8];
    uint4 kpre1 = *(const uint4*)&Kh[(size_t)(kt0*64 + r1)*HD + s1*8];
    uint4 vpre0 = *(const uint4*)&Vh[(size_t)r0*SEQ + kt0*64 + s0*8];
    uint4 vpre1 = *(const uint4*)&Vh[(size_t)r1*SEQ + kt0*64 + s1*8];

    const float SCL = 0.125f * 1.44269504088896f;  // 1/sqrt(64) * log2(e)
    bf16* pl = &Pl[w][0];

    for (int kt = kt0; kt <= kt1; kt++) {
        __syncthreads();                       // prev readers done
        *(uint4*)&Kt[p0*8] = kpre0;
        *(uint4*)&Kt[p1*8] = kpre1;
        *(uint4*)&Vt[p0*8] = vpre0;
        *(uint4*)&Vt[p1*8] = vpre1;
        __syncthreads();                       // tiles visible

        if (kt < kt1) {                        // prefetch next tile — latency spans compute
            kpre0 = *(const uint4*)&Kh[(size_t)((kt+1)*64 + r0)*HD + s0*8];
            kpre1 = *(const uint4*)&Kh[(size_t)((kt+1)*64 + r1)*HD + s1*8];
            vpre0 = *(const uint4*)&Vh[(size_t)r0*SEQ + (kt+1)*64 + s0*8];
            vpre1 = *(const uint4*)&Vh[(size_t)r1*SEQ + (kt+1)*64 + s1*8];
        }

        // S^T = K·Q^T
        f32x4 sf[4];
#pragma unroll
        for (int nt = 0; nt < 4; nt++) sf[nt] = (f32x4){0.f,0.f,0.f,0.f};
#pragma unroll
        for (int nt = 0; nt < 4; nt++) {
            int r = nt*16 + l16;
            bf16x8 kfa = *(const bf16x8*)&Kt[r*64 + ((quad ^ (r&7))*8)];
            bf16x8 kfb = *(const bf16x8*)&Kt[r*64 + (((4+quad) ^ (r&7))*8)];
            sf[nt] = mfma16(kfa, qf0, sf[nt]);
            sf[nt] = mfma16(kfb, qf1, sf[nt]);
        }

        // streaming softmax, fixed max=0; packed b64 P writes to [qrow][key]
        const bool diag = (kt == qt);
        const int qg = qt*64 + w*16 + l16;
#pragma unroll
        for (int nt = 0; nt < 4; nt++) {
            bf16x4 t4;
#pragma unroll
            for (int rr = 0; rr < 4; rr++) {
                float s = sf[nt][rr] * SCL;
                if (diag && (kt*64 + nt*16 + quad*4 + rr) > qg) s = -1e30f;
                float p = __builtin_amdgcn_exp2f(s);
                lsum += p;
                t4[rr] = (bf16)p;
            }
            *(bf16x4*)&pl[l16*72 + nt*16 + quad*4] = t4;
        }

        // O += P·V
        bf16x8 pa0 = *(const bf16x8*)&pl[l16*72 + quad*8];
        bf16x8 pa1 = *(const bf16x8*)&pl[l16*72 + 32 + quad*8];
#pragma unroll
        for (int dm = 0; dm < 4; dm++) {
            int r = dm*16 + l16;
            bf16x8 vva = *(const bf16x8*)&Vt[r*64 + ((quad ^ (r&7))*8)];
            bf16x8 vvb = *(const bf16x8*)&Vt[r*64 + (((4+quad) ^ (r&7))*8)];
            of[dm] = mfma16(pa0, vva, of[dm]);
            of[dm] = mfma16(pa1, vvb, of[dm]);
        }
    }

    lsum += __shfl_xor(lsum, 16);
    lsum += __shfl_xor(lsum, 32);

    if (qt < 8) {
        float linv[4];
#pragma unroll
        for (int rr = 0; rr < 4; rr++)
            linv[rr] = 1.0f / __shfl(lsum, quad*4 + rr);
#pragma unroll
        for (int rr = 0; rr < 4; rr++) {
            int g = b*SEQ + qt*64 + w*16 + quad*4 + rr;
#pragma unroll
            for (int dm = 0; dm < 4; dm++)
                attnout[(size_t)g*DIM + h*HD + dm*16 + l16] = (bf16)(of[dm][rr] * linv[rr]);
        }
    } else {
        size_t slot = ((size_t)bh*24 + (qt - 8))*2 + chunk;
        bf16* Os = Opart + slot*4096;
        float* ls = lpart + slot*64;
        if (quad == 0) ls[w*16 + l16] = lsum;
#pragma unroll
        for (int rr = 0; rr < 4; rr++) {
            int row = w*16 + quad*4 + rr;
#pragma unroll
            for (int dm = 0; dm < 4; dm++)
                Os[(size_t)row*64 + dm*16 + l16] = (bf16)of[dm][rr];
        }
    }
}

// ---------------- merge partials for qt>=8 ----------------
__global__ __launch_bounds__(256) void merge_kernel(
    const bf16* __restrict__ Opart, const float* __restrict__ lpart,
    bf16* __restrict__ attnout)
{
    const int qi = blockIdx.x;
    const int bh = blockIdx.y;
    const int b = bh / NH, h = bh - b*NH;
    const int t = threadIdx.x;
    const int row = t >> 2, cs = t & 3;

    size_t slot0 = ((size_t)bh*24 + qi)*2;
    const bf16* O0 = Opart + slot0*4096 + (size_t)row*64 + cs*16;
    const bf16* O1 = O0 + 4096;
    float inv = 1.0f / (lpart[slot0*64 + row] + lpart[(slot0+1)*64 + row]);

    bf16x8 a0 = *(const bf16x8*)O0;
    bf16x8 a1 = *(const bf16x8*)(O0 + 8);
    bf16x8 b0 = *(const bf16x8*)O1;
    bf16x8 b1 = *(const bf16x8*)(O1 + 8);
    bf16x8 o0, o1;
#pragma unroll
    for (int j = 0; j < 8; j++) {
        o0[j] = (bf16)(((float)a0[j] + (float)b0[j]) * inv);
        o1[j] = (bf16)(((float)a1[j] + (float)b1[j]) * inv);
    }
    size_t o = ((size_t)b*SEQ + (8 + qi)*64 + row)*DIM + h*HD + cs*16;
    *(bf16x8*)&attnout[o]     = o0;
    *(bf16x8*)&attnout[o + 8] = o1;
}

// ---------------- Proj GEMM (single-buffer m97): [4096,768]x[768,768]+bias -> fp32 ----------------
__global__ __launch_bounds__(256) void proj_gemm(
    const bf16* __restrict__ A,
    const bf16* __restrict__ Bt,
    const float* __restrict__ bias,
    float* __restrict__ out)
{
    __shared__ bf16 As[128*32];
    __shared__ bf16 Bs[128*32];
    const int K = DIM;
    const int tid = threadIdx.x;
    const int row0 = blockIdx.y * 128, col0 = blockIdx.x * 128;
    const int w = tid >> 6, lane = tid & 63, quad = lane >> 4, l16 = lane & 15;
    const int wy = w >> 1, wx = w & 1;

    f32x4 acc[4][4];
#pragma unroll
    for (int mi = 0; mi < 4; mi++)
#pragma unroll
        for (int ni = 0; ni < 4; ni++)
            acc[mi][ni] = (f32x4){0.f,0.f,0.f,0.f};

    for (int k0 = 0; k0 < K; k0 += BK) {
        __syncthreads();
        stage128x32(A  + (size_t)row0*K + k0, K, As, w, lane);
        stage128x32(Bt + (size_t)col0*K + k0, K, Bs, w, lane);
        __syncthreads();
        bf16x8 af[4], bfv[4];
#pragma unroll
        for (int mi = 0; mi < 4; mi++)
            af[mi] = frag128x32(As, wy*64 + mi*16 + l16, quad);
#pragma unroll
        for (int ni = 0; ni < 4; ni++)
            bfv[ni] = frag128x32(Bs, wx*64 + ni*16 + l16, quad);
#pragma unroll
        for (int mi = 0; mi < 4; mi++)
#pragma unroll
            for (int ni = 0; ni < 4; ni++)
                acc[mi][ni] = mfma16(af[mi], bfv[ni], acc[mi][ni]);
    }

#pragma unroll
    for (int mi = 0; mi < 4; mi++)
#pragma unroll
        for (int ni = 0; ni < 4; ni++)
#pragma unroll
            for (int rr = 0; rr < 4; rr++) {
                int r = row0 + wy*64 + mi*16 + quad*4 + rr;
                int c = col0 + wx*64 + ni*16 + l16;
                out[(size_t)r*DIM + c] = acc[mi][ni][rr] + bias[c];
            }
}

extern "C" void kernel_launch(void* const* d_in, const int* in_sizes, int n_in,
                              void* d_out, int out_size, void* d_ws, size_t ws_size,
                              hipStream_t stream) {
    const float* x     = (const float*)d_in[0];
    const float* Wqkv  = (const float*)d_in[1];
    const float* bqkv  = (const float*)d_in[2];
    const float* Wproj = (const float*)d_in[3];
    const float* bproj = (const float*)d_in[4];
    float* out = (float*)d_out;

    bf16* xb   = (bf16*)d_ws;                       // 4096*768     (dead after qkv_gemm)
    bf16* Wqt  = xb  + (size_t)M_TOT*DIM;           // 2304*768     (dead after qkv_gemm)
    bf16* Wpt  = Wqt + (size_t)NQKV*DIM;            // 768*768      (live until proj)
    bf16* qkvb = Wpt + (size_t)DIM*DIM;             // 3*4096*768
    bf16* attn = qkvb + (size_t)3*M_TOT*DIM;        // 4096*768

    bf16*  Opart = xb;
    float* lpart = (float*)(xb + (size_t)24*24*2*4096);

    const size_t headsz = (size_t)BATCH*NH*SEQ*HD;

    prep_kernel<<<TQK_TILES + TP_TILES + CAST_BLOCKS, 256, 0, stream>>>(
        x, Wqkv, Wproj, xb, Wqt, Wpt);
    qkv_gemm<<<dim3(NQKV/128, M_TOT/128), 256, 0, stream>>>(xb, Wqt, bqkv, qkvb);
    attn_kernel<<<dim3(2, SEQ/64, BATCH*NH), 256, 0, stream>>>(
        qkvb, qkvb + headsz, qkvb + 2*headsz, attn, Opart, lpart);
    merge_kernel<<<dim3(24, BATCH*NH), 256, 0, stream>>>(Opart, lpart, attn);
    proj_gemm<<<dim3(DIM/128, M_TOT/128), 256, 0, stream>>>(attn, Wpt, bproj, out);
}